// Round 2
// baseline (363.525 us; speedup 1.0000x reference)
//
#include <hip/hip_runtime.h>
#include <math.h>

// Problem constants (from reference)
constexpr int    N       = 8388608;   // B
constexpr int    THREADS = 256;
constexpr int    BLOCKS  = 2048;      // keeps partials workspace at 2048*9*8 = 144 KiB
constexpr int    CHUNK   = 8;         // elements per thread per chunk (2 x float4)
constexpr int    ITERS   = N / (BLOCKS * THREADS * CHUNK);  // = 2, exact
constexpr int    NSUMS   = 9;
// sum layout: 0:Σs 1:Σm 2:Σl 3:Σs² 4:Σm² 5:Σl² 6:Σsm 7:Σsl 8:Σml

static_assert(ITERS == 2, "grid math");

// native vector type for __builtin_nontemporal_store (HIP float4 is a class -> rejected)
using f32x4 = __attribute__((ext_vector_type(4))) float;

__device__ inline void nt_store4(float* p, float a, float b, float c, float d) {
    f32x4 v = {a, b, c, d};
    __builtin_nontemporal_store(v, (f32x4*)p);
}

__device__ inline double wave_reduce(double x) {
#pragma unroll
    for (int off = 32; off > 0; off >>= 1)
        x += __shfl_down(x, off, 64);
    return x;
}

__device__ inline void elem_compute(float cq, float pq, float u, int a, float sc, float fq,
                                    float ms, float inv_ms,
                                    float alpha, float beta, float gamma,
                                    float& rs, float& rm, float& rl, float& tot)
{
    rs = cq - pq;
    float stop_r = (u < 0.3f) ? 0.5f : ((u > 0.7f) ? -0.5f : 0.0f);
    float cont = (u > 0.5f) ? (0.5f * u) : (-0.5f * (1.0f - u));
    cont -= (sc > 0.8f * ms) ? 0.3f : 0.0f;   // 0.8f*20.0f == 16.0f exactly, matches ref
    float t = sc * inv_ms;
    rm = ((a == 0) ? stop_r : cont) - 0.1f * t;
    rl = fq + 0.5f * (1.0f - t);
    tot = alpha * rs + beta * rm + gamma * rl;
}

// Process one 8-element chunk held entirely in registers.
// Chunk c covers elements [8c, 8c+8). Output regions:
//   total_reward : out[e]            (aligned, 2x float4)
//   r_short      : out[N+1+e]        (unaligned by +1)
//   r_mid        : out[2N+1+e]
//   r_long       : out[3N+1+e]
// For the +1 regions: elements b+3..b+6 form an aligned float4 entirely from
// this lane's registers; elements b+7..b+10 = {my r7, next-lane r0,r1,r2}
// (one shuffle-assembled aligned float4, lanes 0..62). Lane 0 patches its
// leading 3 scalars, lane 63 its trailing scalar.
__device__ inline void process_chunk(
    float4 qa, float4 qb, float4 pa, float4 pb,
    float4 ua, float4 ub, int4 aa, int4 ab,
    float4 sa, float4 sb, float4 fa, float4 fb,
    int chunk, int lane,
    float ms, float inv_ms, float alpha, float beta, float gamma,
    float* __restrict__ out, double (&acc)[NSUMS])
{
    float qc[8] = {qa.x, qa.y, qa.z, qa.w, qb.x, qb.y, qb.z, qb.w};
    float pc[8] = {pa.x, pa.y, pa.z, pa.w, pb.x, pb.y, pb.z, pb.w};
    float uc[8] = {ua.x, ua.y, ua.z, ua.w, ub.x, ub.y, ub.z, ub.w};
    int   av[8] = {aa.x, aa.y, aa.z, aa.w, ab.x, ab.y, ab.z, ab.w};
    float sv[8] = {sa.x, sa.y, sa.z, sa.w, sb.x, sb.y, sb.z, sb.w};
    float fv[8] = {fa.x, fa.y, fa.z, fa.w, fb.x, fb.y, fb.z, fb.w};

    float rs[8], rm[8], rl[8], tt[8];
#pragma unroll
    for (int k = 0; k < 8; ++k) {
        elem_compute(qc[k], pc[k], uc[k], av[k], sv[k], fv[k],
                     ms, inv_ms, alpha, beta, gamma,
                     rs[k], rm[k], rl[k], tt[k]);
        double ds = (double)rs[k], dm = (double)rm[k], dl = (double)rl[k];
        acc[0] += ds;      acc[1] += dm;      acc[2] += dl;
        acc[3] += ds * ds; acc[4] += dm * dm; acc[5] += dl * dl;
        acc[6] += ds * dm; acc[7] += ds * dl; acc[8] += dm * dl;
    }

    const int b = chunk * CHUNK;   // element base, multiple of 8

    // total_reward: aligned, streaming (never re-read) -> non-temporal
    nt_store4(out + b,     tt[0], tt[1], tt[2], tt[3]);
    nt_store4(out + b + 4, tt[4], tt[5], tt[6], tt[7]);

    // fully-local aligned quads for the +1 regions: elements b+3..b+6
    nt_store4(out +     N + 4 + b, rs[3], rs[4], rs[5], rs[6]);
    nt_store4(out + 2 * N + 4 + b, rm[3], rm[4], rm[5], rm[6]);
    nt_store4(out + 3 * N + 4 + b, rl[3], rl[4], rl[5], rl[6]);

    // shuffle-assembled quads: elements b+7..b+10 = {r7, next r0, r1, r2}
    float sn0 = __shfl_down(rs[0], 1, 64);
    float sn1 = __shfl_down(rs[1], 1, 64);
    float sn2 = __shfl_down(rs[2], 1, 64);
    float mn0 = __shfl_down(rm[0], 1, 64);
    float mn1 = __shfl_down(rm[1], 1, 64);
    float mn2 = __shfl_down(rm[2], 1, 64);
    float ln0 = __shfl_down(rl[0], 1, 64);
    float ln1 = __shfl_down(rl[1], 1, 64);
    float ln2 = __shfl_down(rl[2], 1, 64);

    if (lane < 63) {
        nt_store4(out +     N + 8 + b, rs[7], sn0, sn1, sn2);
        nt_store4(out + 2 * N + 8 + b, rm[7], mn0, mn1, mn2);
        nt_store4(out + 3 * N + 8 + b, rl[7], ln0, ln1, ln2);
    }
    if (lane == 0) {
        out[    N + 1 + b] = rs[0]; out[    N + 2 + b] = rs[1]; out[    N + 3 + b] = rs[2];
        out[2 * N + 1 + b] = rm[0]; out[2 * N + 2 + b] = rm[1]; out[2 * N + 3 + b] = rm[2];
        out[3 * N + 1 + b] = rl[0]; out[3 * N + 2 + b] = rl[1]; out[3 * N + 3 + b] = rl[2];
    }
    if (lane == 63) {
        out[    N + 8 + b] = rs[7];   // element b+7 at float index N+1+(b+7)
        out[2 * N + 8 + b] = rm[7];
        out[3 * N + 8 + b] = rl[7];
    }
}

__global__ __launch_bounds__(THREADS, 4) void reward_main(
    const float* __restrict__ cq, const float* __restrict__ pq,
    const float* __restrict__ un, const int*  __restrict__ ac,
    const float* __restrict__ sc, const float* __restrict__ fq,
    const float* __restrict__ alpha_p, const float* __restrict__ beta_p,
    const float* __restrict__ gamma_p, const int* __restrict__ ms_p,
    float* __restrict__ out, double* __restrict__ partials)
{
    const float alpha = alpha_p[0], beta = beta_p[0], gamma = gamma_p[0];
    const float ms = (float)ms_p[0];
    const float inv_ms = 1.0f / ms;

    const float4* cq4 = (const float4*)cq;
    const float4* pq4 = (const float4*)pq;
    const float4* un4 = (const float4*)un;
    const int4*   ac4 = (const int4*)ac;
    const float4* sc4 = (const float4*)sc;
    const float4* fq4 = (const float4*)fq;

    double acc[NSUMS];
#pragma unroll
    for (int s = 0; s < NSUMS; ++s) acc[s] = 0.0;

    const int tid  = blockIdx.x * THREADS + threadIdx.x;   // 0 .. 524287
    const int lane = threadIdx.x & 63;

    // Two chunks per thread; issue ALL 24 loads before any compute so up to
    // 384 B/wave are in flight (latency hiding), then consume in order.
    const int c0 = tid;                       // chunk ids
    const int c1 = tid + BLOCKS * THREADS;

    const int i0 = 2 * c0, i1 = 2 * c1;

    float4 Qa0 = cq4[i0], Qb0 = cq4[i0 + 1];
    float4 Pa0 = pq4[i0], Pb0 = pq4[i0 + 1];
    float4 Ua0 = un4[i0], Ub0 = un4[i0 + 1];
    int4   Aa0 = ac4[i0], Ab0 = ac4[i0 + 1];
    float4 Sa0 = sc4[i0], Sb0 = sc4[i0 + 1];
    float4 Fa0 = fq4[i0], Fb0 = fq4[i0 + 1];

    float4 Qa1 = cq4[i1], Qb1 = cq4[i1 + 1];
    float4 Pa1 = pq4[i1], Pb1 = pq4[i1 + 1];
    float4 Ua1 = un4[i1], Ub1 = un4[i1 + 1];
    int4   Aa1 = ac4[i1], Ab1 = ac4[i1 + 1];
    float4 Sa1 = sc4[i1], Sb1 = sc4[i1 + 1];
    float4 Fa1 = fq4[i1], Fb1 = fq4[i1 + 1];

    process_chunk(Qa0, Qb0, Pa0, Pb0, Ua0, Ub0, Aa0, Ab0, Sa0, Sb0, Fa0, Fb0,
                  c0, lane, ms, inv_ms, alpha, beta, gamma, out, acc);
    process_chunk(Qa1, Qb1, Pa1, Pb1, Ua1, Ub1, Aa1, Ab1, Sa1, Sb1, Fa1, Fb1,
                  c1, lane, ms, inv_ms, alpha, beta, gamma, out, acc);

    // block reduction of 9 sums
    __shared__ double red[NSUMS][THREADS / 64];
    const int wave = threadIdx.x >> 6;
#pragma unroll
    for (int s = 0; s < NSUMS; ++s) {
        double w = wave_reduce(acc[s]);
        if (lane == 0) red[s][wave] = w;
    }
    __syncthreads();
    if (threadIdx.x == 0) {
#pragma unroll
        for (int s = 0; s < NSUMS; ++s) {
            double t = 0.0;
#pragma unroll
            for (int w = 0; w < THREADS / 64; ++w) t += red[s][w];
            partials[blockIdx.x * NSUMS + s] = t;
        }
    }
}

__global__ __launch_bounds__(256) void reward_finish(const double* __restrict__ partials,
                                                     float* __restrict__ out)
{
    double loc[NSUMS];
#pragma unroll
    for (int s = 0; s < NSUMS; ++s) loc[s] = 0.0;
    for (int i = threadIdx.x; i < BLOCKS; i += 256) {
#pragma unroll
        for (int s = 0; s < NSUMS; ++s) loc[s] += partials[i * NSUMS + s];
    }
    __shared__ double red[NSUMS][4];
    const int lane = threadIdx.x & 63;
    const int wave = threadIdx.x >> 6;
#pragma unroll
    for (int s = 0; s < NSUMS; ++s) {
        double w = wave_reduce(loc[s]);
        if (lane == 0) red[s][wave] = w;
    }
    __syncthreads();
    if (threadIdx.x == 0) {
        double S[NSUMS];
#pragma unroll
        for (int s = 0; s < NSUMS; ++s)
            S[s] = red[s][0] + red[s][1] + red[s][2] + red[s][3];

        const double n = (double)N;
        double mx = S[0] / n, mm = S[1] / n, ml = S[2] / n;
        double cov_sm = S[6] / n - mx * mm;
        double cov_sl = S[7] / n - mx * ml;
        double cov_ml = S[8] / n - mm * ml;
        double sdS = sqrt((S[3] - n * mx * mx) / (n - 1.0)) + 1e-8;
        double sdM = sqrt((S[4] - n * mm * mm) / (n - 1.0)) + 1e-8;
        double sdL = sqrt((S[5] - n * ml * ml) / (n - 1.0)) + 1e-8;
        double c1 = cov_sm / (sdS * sdM);
        double c2 = cov_sl / (sdS * sdL);
        double c3 = cov_ml / (sdM * sdL);
        out[N] = (float)(c1 * c1 + c2 * c2 + c3 * c3);   // ORTHO_W = 1
    }
}

extern "C" void kernel_launch(void* const* d_in, const int* in_sizes, int n_in,
                              void* d_out, int out_size, void* d_ws, size_t ws_size,
                              hipStream_t stream)
{
    const float* cq   = (const float*)d_in[0];
    const float* pq   = (const float*)d_in[1];
    const float* un   = (const float*)d_in[2];
    const int*   ac   = (const int*)d_in[3];
    const float* sc   = (const float*)d_in[4];
    const float* fq   = (const float*)d_in[5];
    const float* alp  = (const float*)d_in[6];
    const float* bet  = (const float*)d_in[7];
    const float* gam  = (const float*)d_in[8];
    const int*   msp  = (const int*)d_in[9];
    float*  out      = (float*)d_out;
    double* partials = (double*)d_ws;   // 2048 * 9 * 8 B = 144 KiB

    reward_main<<<BLOCKS, THREADS, 0, stream>>>(cq, pq, un, ac, sc, fq,
                                                alp, bet, gam, msp, out, partials);
    reward_finish<<<1, 256, 0, stream>>>(partials, out);
}

// Round 4
// 308.033 us; speedup vs baseline: 1.1802x; 1.1802x over previous
//
#include <hip/hip_runtime.h>
#include <math.h>

// Problem constants (from reference)
constexpr int    N       = 8388608;   // B
constexpr int    THREADS = 256;
constexpr int    BLOCKS  = 2048;      // keeps partials workspace at 2048*9*8 = 144 KiB
constexpr int    CHUNK   = 8;         // elements per thread per chunk (2 x float4)
constexpr int    ITERS   = N / (BLOCKS * THREADS * CHUNK);  // = 2, exact
constexpr int    NSUMS   = 9;
// sum layout: 0:Σs 1:Σm 2:Σl 3:Σs² 4:Σm² 5:Σl² 6:Σsm 7:Σsl 8:Σml

static_assert(ITERS == 2, "grid math");

__device__ inline double wave_reduce(double x) {
#pragma unroll
    for (int off = 32; off > 0; off >>= 1)
        x += __shfl_down(x, off, 64);
    return x;
}

__device__ inline void elem_compute(float cq, float pq, float u, int a, float sc, float fq,
                                    float ms, float inv_ms,
                                    float alpha, float beta, float gamma,
                                    float& rs, float& rm, float& rl, float& tot)
{
    rs = cq - pq;
    float stop_r = (u < 0.3f) ? 0.5f : ((u > 0.7f) ? -0.5f : 0.0f);
    float cont = (u > 0.5f) ? (0.5f * u) : (-0.5f * (1.0f - u));
    cont -= (sc > 0.8f * ms) ? 0.3f : 0.0f;   // 0.8f*20.0f == 16.0f exactly, matches ref
    float t = sc * inv_ms;
    rm = ((a == 0) ? stop_r : cont) - 0.1f * t;
    rl = fq + 0.5f * (1.0f - t);
    tot = alpha * rs + beta * rm + gamma * rl;
}

// Process one 8-element chunk held entirely in registers.
// Chunk c covers elements [8c, 8c+8). Output regions:
//   total_reward : out[e]            (aligned, 2x float4)
//   r_short      : out[N+1+e]        (unaligned by +1)
//   r_mid        : out[2N+1+e]
//   r_long       : out[3N+1+e]
// For the +1 regions: elements b+3..b+6 form an aligned float4 entirely from
// this lane's registers; elements b+7..b+10 = {my r7, next-lane r0,r1,r2}
// (one shuffle-assembled aligned float4, lanes 0..62). Lane 0 patches its
// leading 3 scalars, lane 63 its trailing scalar.
// Plain stores throughout: L2 write-combining merges them into full dirty
// lines (WRITE_SIZE == logical 134 MB, verified round 0). NT stores caused
// 2x write amplification (round 2) — do not reintroduce.
__device__ inline void process_chunk(
    float4 qa, float4 qb, float4 pa, float4 pb,
    float4 ua, float4 ub, int4 aa, int4 ab,
    float4 sa, float4 sb, float4 fa, float4 fb,
    int chunk, int lane,
    float ms, float inv_ms, float alpha, float beta, float gamma,
    float* __restrict__ out, double (&acc)[NSUMS])
{
    float qc[8] = {qa.x, qa.y, qa.z, qa.w, qb.x, qb.y, qb.z, qb.w};
    float pc[8] = {pa.x, pa.y, pa.z, pa.w, pb.x, pb.y, pb.z, pb.w};
    float uc[8] = {ua.x, ua.y, ua.z, ua.w, ub.x, ub.y, ub.z, ub.w};
    int   av[8] = {aa.x, aa.y, aa.z, aa.w, ab.x, ab.y, ab.z, ab.w};
    float sv[8] = {sa.x, sa.y, sa.z, sa.w, sb.x, sb.y, sb.z, sb.w};
    float fv[8] = {fa.x, fa.y, fa.z, fa.w, fb.x, fb.y, fb.z, fb.w};

    float rs[8], rm[8], rl[8], tt[8];
#pragma unroll
    for (int k = 0; k < 8; ++k) {
        elem_compute(qc[k], pc[k], uc[k], av[k], sv[k], fv[k],
                     ms, inv_ms, alpha, beta, gamma,
                     rs[k], rm[k], rl[k], tt[k]);
        double ds = (double)rs[k], dm = (double)rm[k], dl = (double)rl[k];
        acc[0] += ds;      acc[1] += dm;      acc[2] += dl;
        acc[3] += ds * ds; acc[4] += dm * dm; acc[5] += dl * dl;
        acc[6] += ds * dm; acc[7] += ds * dl; acc[8] += dm * dl;
    }

    const int b = chunk * CHUNK;   // element base, multiple of 8

    // total_reward: aligned, lane-contiguous
    *(float4*)(out + b)     = make_float4(tt[0], tt[1], tt[2], tt[3]);
    *(float4*)(out + b + 4) = make_float4(tt[4], tt[5], tt[6], tt[7]);

    // fully-local aligned quads for the +1 regions: elements b+3..b+6
    *(float4*)(out +     N + 4 + b) = make_float4(rs[3], rs[4], rs[5], rs[6]);
    *(float4*)(out + 2 * N + 4 + b) = make_float4(rm[3], rm[4], rm[5], rm[6]);
    *(float4*)(out + 3 * N + 4 + b) = make_float4(rl[3], rl[4], rl[5], rl[6]);

    // shuffle-assembled quads: elements b+7..b+10 = {r7, next r0, r1, r2}
    float sn0 = __shfl_down(rs[0], 1, 64);
    float sn1 = __shfl_down(rs[1], 1, 64);
    float sn2 = __shfl_down(rs[2], 1, 64);
    float mn0 = __shfl_down(rm[0], 1, 64);
    float mn1 = __shfl_down(rm[1], 1, 64);
    float mn2 = __shfl_down(rm[2], 1, 64);
    float ln0 = __shfl_down(rl[0], 1, 64);
    float ln1 = __shfl_down(rl[1], 1, 64);
    float ln2 = __shfl_down(rl[2], 1, 64);

    if (lane < 63) {
        *(float4*)(out +     N + 8 + b) = make_float4(rs[7], sn0, sn1, sn2);
        *(float4*)(out + 2 * N + 8 + b) = make_float4(rm[7], mn0, mn1, mn2);
        *(float4*)(out + 3 * N + 8 + b) = make_float4(rl[7], ln0, ln1, ln2);
    }
    if (lane == 0) {
        out[    N + 1 + b] = rs[0]; out[    N + 2 + b] = rs[1]; out[    N + 3 + b] = rs[2];
        out[2 * N + 1 + b] = rm[0]; out[2 * N + 2 + b] = rm[1]; out[2 * N + 3 + b] = rm[2];
        out[3 * N + 1 + b] = rl[0]; out[3 * N + 2 + b] = rl[1]; out[3 * N + 3 + b] = rl[2];
    }
    if (lane == 63) {
        out[    N + 8 + b] = rs[7];   // element b+7 at float index N+1+(b+7)
        out[2 * N + 8 + b] = rm[7];
        out[3 * N + 8 + b] = rl[7];
    }
}

__global__ __launch_bounds__(THREADS) void reward_main(
    const float* __restrict__ cq, const float* __restrict__ pq,
    const float* __restrict__ un, const int*  __restrict__ ac,
    const float* __restrict__ sc, const float* __restrict__ fq,
    const float* __restrict__ alpha_p, const float* __restrict__ beta_p,
    const float* __restrict__ gamma_p, const int* __restrict__ ms_p,
    float* __restrict__ out, double* __restrict__ partials)
{
    const float alpha = alpha_p[0], beta = beta_p[0], gamma = gamma_p[0];
    const float ms = (float)ms_p[0];
    const float inv_ms = 1.0f / ms;

    const float4* cq4 = (const float4*)cq;
    const float4* pq4 = (const float4*)pq;
    const float4* un4 = (const float4*)un;
    const int4*   ac4 = (const int4*)ac;
    const float4* sc4 = (const float4*)sc;
    const float4* fq4 = (const float4*)fq;

    double acc[NSUMS];
#pragma unroll
    for (int s = 0; s < NSUMS; ++s) acc[s] = 0.0;

    const int tid  = blockIdx.x * THREADS + threadIdx.x;   // 0 .. 524287
    const int lane = threadIdx.x & 63;

    // Two chunks per thread; issue loads of both chunks before compute so the
    // scheduler can overlap chunk-1 loads with chunk-0 compute.
    const int c0 = tid;                       // chunk ids
    const int c1 = tid + BLOCKS * THREADS;

    const int i0 = 2 * c0, i1 = 2 * c1;

    float4 Qa0 = cq4[i0], Qb0 = cq4[i0 + 1];
    float4 Pa0 = pq4[i0], Pb0 = pq4[i0 + 1];
    float4 Ua0 = un4[i0], Ub0 = un4[i0 + 1];
    int4   Aa0 = ac4[i0], Ab0 = ac4[i0 + 1];
    float4 Sa0 = sc4[i0], Sb0 = sc4[i0 + 1];
    float4 Fa0 = fq4[i0], Fb0 = fq4[i0 + 1];

    float4 Qa1 = cq4[i1], Qb1 = cq4[i1 + 1];
    float4 Pa1 = pq4[i1], Pb1 = pq4[i1 + 1];
    float4 Ua1 = un4[i1], Ub1 = un4[i1 + 1];
    int4   Aa1 = ac4[i1], Ab1 = ac4[i1 + 1];
    float4 Sa1 = sc4[i1], Sb1 = sc4[i1 + 1];
    float4 Fa1 = fq4[i1], Fb1 = fq4[i1 + 1];

    process_chunk(Qa0, Qb0, Pa0, Pb0, Ua0, Ub0, Aa0, Ab0, Sa0, Sb0, Fa0, Fb0,
                  c0, lane, ms, inv_ms, alpha, beta, gamma, out, acc);
    process_chunk(Qa1, Qb1, Pa1, Pb1, Ua1, Ub1, Aa1, Ab1, Sa1, Sb1, Fa1, Fb1,
                  c1, lane, ms, inv_ms, alpha, beta, gamma, out, acc);

    // block reduction of 9 sums
    __shared__ double red[NSUMS][THREADS / 64];
    const int wave = threadIdx.x >> 6;
#pragma unroll
    for (int s = 0; s < NSUMS; ++s) {
        double w = wave_reduce(acc[s]);
        if (lane == 0) red[s][wave] = w;
    }
    __syncthreads();
    if (threadIdx.x == 0) {
#pragma unroll
        for (int s = 0; s < NSUMS; ++s) {
            double t = 0.0;
#pragma unroll
            for (int w = 0; w < THREADS / 64; ++w) t += red[s][w];
            partials[blockIdx.x * NSUMS + s] = t;
        }
    }
}

__global__ __launch_bounds__(256) void reward_finish(const double* __restrict__ partials,
                                                     float* __restrict__ out)
{
    double loc[NSUMS];
#pragma unroll
    for (int s = 0; s < NSUMS; ++s) loc[s] = 0.0;
    for (int i = threadIdx.x; i < BLOCKS; i += 256) {
#pragma unroll
        for (int s = 0; s < NSUMS; ++s) loc[s] += partials[i * NSUMS + s];
    }
    __shared__ double red[NSUMS][4];
    const int lane = threadIdx.x & 63;
    const int wave = threadIdx.x >> 6;
#pragma unroll
    for (int s = 0; s < NSUMS; ++s) {
        double w = wave_reduce(loc[s]);
        if (lane == 0) red[s][wave] = w;
    }
    __syncthreads();
    if (threadIdx.x == 0) {
        double S[NSUMS];
#pragma unroll
        for (int s = 0; s < NSUMS; ++s)
            S[s] = red[s][0] + red[s][1] + red[s][2] + red[s][3];

        const double n = (double)N;
        double mx = S[0] / n, mm = S[1] / n, ml = S[2] / n;
        double cov_sm = S[6] / n - mx * mm;
        double cov_sl = S[7] / n - mx * ml;
        double cov_ml = S[8] / n - mm * ml;
        double sdS = sqrt((S[3] - n * mx * mx) / (n - 1.0)) + 1e-8;
        double sdM = sqrt((S[4] - n * mm * mm) / (n - 1.0)) + 1e-8;
        double sdL = sqrt((S[5] - n * ml * ml) / (n - 1.0)) + 1e-8;
        double c1 = cov_sm / (sdS * sdM);
        double c2 = cov_sl / (sdS * sdL);
        double c3 = cov_ml / (sdM * sdL);
        out[N] = (float)(c1 * c1 + c2 * c2 + c3 * c3);   // ORTHO_W = 1
    }
}

extern "C" void kernel_launch(void* const* d_in, const int* in_sizes, int n_in,
                              void* d_out, int out_size, void* d_ws, size_t ws_size,
                              hipStream_t stream)
{
    const float* cq   = (const float*)d_in[0];
    const float* pq   = (const float*)d_in[1];
    const float* un   = (const float*)d_in[2];
    const int*   ac   = (const int*)d_in[3];
    const float* sc   = (const float*)d_in[4];
    const float* fq   = (const float*)d_in[5];
    const float* alp  = (const float*)d_in[6];
    const float* bet  = (const float*)d_in[7];
    const float* gam  = (const float*)d_in[8];
    const int*   msp  = (const int*)d_in[9];
    float*  out      = (float*)d_out;
    double* partials = (double*)d_ws;   // 2048 * 9 * 8 B = 144 KiB

    reward_main<<<BLOCKS, THREADS, 0, stream>>>(cq, pq, un, ac, sc, fq,
                                                alp, bet, gam, msp, out, partials);
    reward_finish<<<1, 256, 0, stream>>>(partials, out);
}

// Round 6
// 301.152 us; speedup vs baseline: 1.2071x; 1.0228x over previous
//
#include <hip/hip_runtime.h>
#include <math.h>

// Problem constants (from reference)
constexpr int    N       = 8388608;   // B
constexpr int    THREADS = 256;
constexpr int    BLOCKS  = 2048;      // keeps partials workspace at 2048*9*8 = 144 KiB
constexpr int    VEC     = 4;
constexpr int    ITERS   = N / (BLOCKS * THREADS * VEC);  // = 4, exact
constexpr int    NSUMS   = 9;
// sum layout: 0:Σs 1:Σm 2:Σl 3:Σs² 4:Σm² 5:Σl² 6:Σsm 7:Σsl 8:Σml

static_assert(ITERS == 4, "grid math");

__device__ inline double wave_reduce(double x) {
#pragma unroll
    for (int off = 32; off > 0; off >>= 1)
        x += __shfl_down(x, off, 64);
    return x;
}

__device__ inline void elem_compute(float cq, float pq, float u, int a, float sc, float fq,
                                    float ms, float inv_ms,
                                    float alpha, float beta, float gamma,
                                    float& rs, float& rm, float& rl, float& tot)
{
    rs = cq - pq;
    float stop_r = (u < 0.3f) ? 0.5f : ((u > 0.7f) ? -0.5f : 0.0f);
    float cont = (u > 0.5f) ? (0.5f * u) : (-0.5f * (1.0f - u));
    cont -= (sc > 0.8f * ms) ? 0.3f : 0.0f;   // 0.8f*20.0f == 16.0f exactly, matches ref
    float t = sc * inv_ms;
    rm = ((a == 0) ? stop_r : cont) - 0.1f * t;
    rl = fq + 0.5f * (1.0f - t);
    tot = alpha * rs + beta * rm + gamma * rl;
}

// One iteration's input tile, held in registers (6 x 16 B = 24 VGPR).
struct InRegs {
    float4 q, p, u, s, f;
    int4   a;
};

__device__ inline void load_set(const float4* __restrict__ cq4, const float4* __restrict__ pq4,
                                const float4* __restrict__ un4, const int4* __restrict__ ac4,
                                const float4* __restrict__ sc4, const float4* __restrict__ fq4,
                                int idx4, InRegs& r)
{
    r.q = cq4[idx4];
    r.p = pq4[idx4];
    r.u = un4[idx4];
    r.a = ac4[idx4];
    r.s = sc4[idx4];
    r.f = fq4[idx4];
}

// Round-0 store scheme (WRITE_SIZE == logical 133 MB, verified):
//   total_reward : aligned float4 at out[4*idx4]
//   +1 regions   : lane j's aligned quad = {my v3, next-lane v0,v1,v2} via shfl;
//                  lane 0 patches 3 leading scalars, lane 63 one trailing scalar.
// Plain stores only — NT stores caused 2x write amplification (round 2).
__device__ inline void process4(const InRegs& r, int idx4, int lane,
                                float ms, float inv_ms,
                                float alpha, float beta, float gamma,
                                float* __restrict__ out, double (&acc)[NSUMS])
{
    float qc[4] = {r.q.x, r.q.y, r.q.z, r.q.w};
    float pc[4] = {r.p.x, r.p.y, r.p.z, r.p.w};
    float uc[4] = {r.u.x, r.u.y, r.u.z, r.u.w};
    int   av[4] = {r.a.x, r.a.y, r.a.z, r.a.w};
    float sv[4] = {r.s.x, r.s.y, r.s.z, r.s.w};
    float fv[4] = {r.f.x, r.f.y, r.f.z, r.f.w};

    float rs[4], rm[4], rl[4], tt[4];
#pragma unroll
    for (int k = 0; k < 4; ++k) {
        elem_compute(qc[k], pc[k], uc[k], av[k], sv[k], fv[k],
                     ms, inv_ms, alpha, beta, gamma,
                     rs[k], rm[k], rl[k], tt[k]);
        double ds = (double)rs[k], dm = (double)rm[k], dl = (double)rl[k];
        acc[0] += ds;      acc[1] += dm;      acc[2] += dl;
        acc[3] += ds * ds; acc[4] += dm * dm; acc[5] += dl * dl;
        acc[6] += ds * dm; acc[7] += ds * dl; acc[8] += dm * dl;
    }

    // total_reward: naturally aligned & lane-contiguous
    *(float4*)(out + 4 * idx4) = make_float4(tt[0], tt[1], tt[2], tt[3]);

    const int b = idx4 * 4;   // element base for this lane

    float s0n = __shfl_down(rs[0], 1, 64);
    float s1n = __shfl_down(rs[1], 1, 64);
    float s2n = __shfl_down(rs[2], 1, 64);
    float m0n = __shfl_down(rm[0], 1, 64);
    float m1n = __shfl_down(rm[1], 1, 64);
    float m2n = __shfl_down(rm[2], 1, 64);
    float l0n = __shfl_down(rl[0], 1, 64);
    float l1n = __shfl_down(rl[1], 1, 64);
    float l2n = __shfl_down(rl[2], 1, 64);

    if (lane < 63) {
        *(float4*)(out +     N + 4 + b) = make_float4(rs[3], s0n, s1n, s2n);
        *(float4*)(out + 2 * N + 4 + b) = make_float4(rm[3], m0n, m1n, m2n);
        *(float4*)(out + 3 * N + 4 + b) = make_float4(rl[3], l0n, l1n, l2n);
    }
    if (lane == 0) {
        out[    N + 1 + b] = rs[0]; out[    N + 2 + b] = rs[1]; out[    N + 3 + b] = rs[2];
        out[2 * N + 1 + b] = rm[0]; out[2 * N + 2 + b] = rm[1]; out[2 * N + 3 + b] = rm[2];
        out[3 * N + 1 + b] = rl[0]; out[3 * N + 2 + b] = rl[1]; out[3 * N + 3 + b] = rl[2];
    }
    if (lane == 63) {
        out[    N + 4 + b] = rs[3];   // element b+3 at float index N+1+(b+3)
        out[2 * N + 4 + b] = rm[3];
        out[3 * N + 4 + b] = rl[3];
    }
}

__global__ __launch_bounds__(THREADS) void reward_main(
    const float* __restrict__ cq, const float* __restrict__ pq,
    const float* __restrict__ un, const int*  __restrict__ ac,
    const float* __restrict__ sc, const float* __restrict__ fq,
    const float* __restrict__ alpha_p, const float* __restrict__ beta_p,
    const float* __restrict__ gamma_p, const int* __restrict__ ms_p,
    float* __restrict__ out, double* __restrict__ partials)
{
    const float alpha = alpha_p[0], beta = beta_p[0], gamma = gamma_p[0];
    const float ms = (float)ms_p[0];
    const float inv_ms = 1.0f / ms;

    const float4* cq4 = (const float4*)cq;
    const float4* pq4 = (const float4*)pq;
    const float4* un4 = (const float4*)un;
    const int4*   ac4 = (const int4*)ac;
    const float4* sc4 = (const float4*)sc;
    const float4* fq4 = (const float4*)fq;

    double acc[NSUMS];
#pragma unroll
    for (int s = 0; s < NSUMS; ++s) acc[s] = 0.0;

    const int tid    = blockIdx.x * THREADS + threadIdx.x;   // 0 .. 524287
    const int lane   = threadIdx.x & 63;
    const int STRIDE = BLOCKS * THREADS;

    // Software-pipelined register double-buffer. Hand-unrolled with named
    // sets A/B (static indexing only — dynamic indexing would spill).
    // sched_barrier(0) after each prefetch pins the loads ABOVE the
    // process/store phase so the compiler cannot sink them to their uses
    // (it did exactly that in rounds 0/2/4: VGPR stayed 56, no pipeline).
    // Steady state: consume waits on a counted vmcnt (next tile's 6 loads
    // still in flight), never a full drain.
    InRegs A, B;

    load_set(cq4, pq4, un4, ac4, sc4, fq4, tid,              A);   // iter 0
    load_set(cq4, pq4, un4, ac4, sc4, fq4, tid + STRIDE,     B);   // iter 1 (prefetch)
    __builtin_amdgcn_sched_barrier(0);

    process4(A, tid,              lane, ms, inv_ms, alpha, beta, gamma, out, acc);
    load_set(cq4, pq4, un4, ac4, sc4, fq4, tid + 2 * STRIDE, A);   // iter 2 (prefetch)
    __builtin_amdgcn_sched_barrier(0);

    process4(B, tid + STRIDE,     lane, ms, inv_ms, alpha, beta, gamma, out, acc);
    load_set(cq4, pq4, un4, ac4, sc4, fq4, tid + 3 * STRIDE, B);   // iter 3 (prefetch)
    __builtin_amdgcn_sched_barrier(0);

    process4(A, tid + 2 * STRIDE, lane, ms, inv_ms, alpha, beta, gamma, out, acc);
    process4(B, tid + 3 * STRIDE, lane, ms, inv_ms, alpha, beta, gamma, out, acc);

    // block reduction of 9 sums
    __shared__ double red[NSUMS][THREADS / 64];
    const int wave = threadIdx.x >> 6;
#pragma unroll
    for (int s = 0; s < NSUMS; ++s) {
        double w = wave_reduce(acc[s]);
        if (lane == 0) red[s][wave] = w;
    }
    __syncthreads();
    if (threadIdx.x == 0) {
#pragma unroll
        for (int s = 0; s < NSUMS; ++s) {
            double t = 0.0;
#pragma unroll
            for (int w = 0; w < THREADS / 64; ++w) t += red[s][w];
            partials[blockIdx.x * NSUMS + s] = t;
        }
    }
}

__global__ __launch_bounds__(256) void reward_finish(const double* __restrict__ partials,
                                                     float* __restrict__ out)
{
    double loc[NSUMS];
#pragma unroll
    for (int s = 0; s < NSUMS; ++s) loc[s] = 0.0;
    for (int i = threadIdx.x; i < BLOCKS; i += 256) {
#pragma unroll
        for (int s = 0; s < NSUMS; ++s) loc[s] += partials[i * NSUMS + s];
    }
    __shared__ double red[NSUMS][4];
    const int lane = threadIdx.x & 63;
    const int wave = threadIdx.x >> 6;
#pragma unroll
    for (int s = 0; s < NSUMS; ++s) {
        double w = wave_reduce(loc[s]);
        if (lane == 0) red[s][wave] = w;
    }
    __syncthreads();
    if (threadIdx.x == 0) {
        double S[NSUMS];
#pragma unroll
        for (int s = 0; s < NSUMS; ++s)
            S[s] = red[s][0] + red[s][1] + red[s][2] + red[s][3];

        const double n = (double)N;
        double mx = S[0] / n, mm = S[1] / n, ml = S[2] / n;
        double cov_sm = S[6] / n - mx * mm;
        double cov_sl = S[7] / n - mx * ml;
        double cov_ml = S[8] / n - mm * ml;
        double sdS = sqrt((S[3] - n * mx * mx) / (n - 1.0)) + 1e-8;
        double sdM = sqrt((S[4] - n * mm * mm) / (n - 1.0)) + 1e-8;
        double sdL = sqrt((S[5] - n * ml * ml) / (n - 1.0)) + 1e-8;
        double c1 = cov_sm / (sdS * sdM);
        double c2 = cov_sl / (sdS * sdL);
        double c3 = cov_ml / (sdM * sdL);
        out[N] = (float)(c1 * c1 + c2 * c2 + c3 * c3);   // ORTHO_W = 1
    }
}

extern "C" void kernel_launch(void* const* d_in, const int* in_sizes, int n_in,
                              void* d_out, int out_size, void* d_ws, size_t ws_size,
                              hipStream_t stream)
{
    const float* cq   = (const float*)d_in[0];
    const float* pq   = (const float*)d_in[1];
    const float* un   = (const float*)d_in[2];
    const int*   ac   = (const int*)d_in[3];
    const float* sc   = (const float*)d_in[4];
    const float* fq   = (const float*)d_in[5];
    const float* alp  = (const float*)d_in[6];
    const float* bet  = (const float*)d_in[7];
    const float* gam  = (const float*)d_in[8];
    const int*   msp  = (const int*)d_in[9];
    float*  out      = (float*)d_out;
    double* partials = (double*)d_ws;   // 2048 * 9 * 8 B = 144 KiB

    reward_main<<<BLOCKS, THREADS, 0, stream>>>(cq, pq, un, ac, sc, fq,
                                                alp, bet, gam, msp, out, partials);
    reward_finish<<<1, 256, 0, stream>>>(partials, out);
}